// Round 7
// baseline (166.724 us; speedup 1.0000x reference)
//
#include <hip/hip_runtime.h>

#define M_ 4
#define K_ 2048
#define D_ 32
#define HW_ 4096
#define NHW_ 32768

// Confirm margin: hard bound on |s_exact - s_approx| for the 3-term bf16 split
// (dropped cl*ql term + split residual + fp32 accum) <= ~3e-3 at dataset-max
// norms. EPS = 0.01 > 3x. conf => K1 is the unique exact argmax (proof: for all
// k != K1, s_exact(k) <= s~(k) + eps <= b2m + EPS < sx). HW-validated in R6.
#define EPS 0.01f

// workspace (bytes) — total 2.03 MB (same budget as the R2-proven layout)
#define CH_OFF 0                        // bf16 hi codebook [4][2048][32] (512 KiB)
#define CL_OFF (M_*K_*D_*2)             // bf16 lo codebook              (512 KiB)
#define HN_OFF (CL_OFF*2)               // f32 -0.5*||c||^2 [4][2048]    (32 KiB)
#define K1_OFF (HN_OFF + M_*K_*4)       // i32 approx argmax [4][32768]  (512 KiB)
#define B2_OFF (K1_OFF + M_*NHW_*4)     // f32 approx 2nd max [4][32768] (512 KiB)

typedef __attribute__((ext_vector_type(8))) short bf16x8;
typedef __attribute__((ext_vector_type(4))) float f32x4;

__device__ __forceinline__ short bf16_rte(float x, float* back) {
    unsigned u = __float_as_uint(x);
    unsigned r = (u + 0x7FFFu + ((u >> 16) & 1u)) >> 16;
    *back = __uint_as_float(r << 16);
    return (short)(r & 0xFFFFu);
}

// ---- kernel 1: codebook -> bf16 hi/lo + (-0.5*||c||^2) ----  (R6-validated)
__global__ __launch_bounds__(256) void prep_kernel(const float* __restrict__ cb,
                                                   unsigned char* __restrict__ ws) {
    int t = blockIdx.x * 256 + threadIdx.x;          // row id = m*K_ + k
    const float* src = cb + (size_t)t * D_;
    short* dh = (short*)(ws + CH_OFF) + (size_t)t * D_;
    short* dl = (short*)(ws + CL_OFF) + (size_t)t * D_;
    float* hn = (float*)(ws + HN_OFF);
    bf16x8 vh[4], vl[4];
    float c2 = 0.f;
    #pragma unroll
    for (int d = 0; d < D_; ++d) {
        float x = src[d];
        float hf, lf;
        short hb = bf16_rte(x, &hf);
        short lb = bf16_rte(x - hf, &lf);
        vh[d >> 3][d & 7] = hb;
        vl[d >> 3][d & 7] = lb;
        c2 = fmaf(x, x, c2);
    }
    #pragma unroll
    for (int i = 0; i < 4; ++i) {
        *(bf16x8*)(dh + i * 8) = vh[i];
        *(bf16x8*)(dl + i * 8) = vl[i];
    }
    hn[t] = -0.5f * c2;
}

__device__ __forceinline__ float score_fp32(const float* __restrict__ q,
                                            const float4* __restrict__ c) {
    float d0 = 0, d1 = 0, d2 = 0, d3 = 0, e0 = 0, e1 = 0, e2 = 0, e3 = 0;
    #pragma unroll
    for (int v = 0; v < 8; ++v) {
        float4 cv = c[v];
        d0 = fmaf(q[v * 4 + 0], cv.x, d0);
        d1 = fmaf(q[v * 4 + 1], cv.y, d1);
        d2 = fmaf(q[v * 4 + 2], cv.z, d2);
        d3 = fmaf(q[v * 4 + 3], cv.w, d3);
        e0 = fmaf(cv.x, cv.x, e0);
        e1 = fmaf(cv.y, cv.y, e1);
        e2 = fmaf(cv.z, cv.z, e2);
        e3 = fmaf(cv.w, cv.w, e3);
    }
    return ((d0 + d1) + (d2 + d3)) - 0.5f * ((e0 + e1) + (e2 + e3));
}

// ---- kernel 2: R6-validated 3-term MFMA + top1(idx)/top2(val); writes k1,b2m ----
// 512 threads = 8 waves. wave w: m = w&3, kh = w>>2 (half of the codebook).
__global__ __launch_bounds__(512, 4) void score_kernel(
        const float* __restrict__ latent,
        const unsigned char* __restrict__ cws,
        int* __restrict__ k1w, float* __restrict__ b2w) {
    __shared__ float s_b1[2][M_][64];
    __shared__ int   s_k1[2][M_][64];
    __shared__ float s_b2[2][M_][64];

    const int tid  = threadIdx.x;
    const int wave = tid >> 6;
    const int L    = tid & 63;
    const int m    = wave & 3;
    const int kh   = wave >> 2;
    const int col  = L & 15;
    const int krow = L >> 4;
    const int posbase = blockIdx.x * 64;
    const int n   = posbase >> 12;
    const int hwb = posbase & (HW_ - 1);

    // q -> bf16 hi/lo B-fragments (R6-validated)
    bf16x8 qh[4], ql[4];
    const float* lp = latent + ((size_t)n * (M_ * D_) + m * D_) * HW_ + hwb;
    #pragma unroll
    for (int g = 0; g < 4; ++g)
        #pragma unroll
        for (int j = 0; j < 8; ++j) {
            float x = lp[(size_t)(krow * 8 + j) * HW_ + g * 16 + col];
            float hf, lf;
            qh[g][j] = bf16_rte(x, &hf);
            ql[g][j] = bf16_rte(x - hf, &lf);
        }

    const short* ah = (const short*)(cws + CH_OFF)
                      + ((size_t)m * K_ + kh * 1024 + col) * D_ + krow * 8;
    const short* al = (const short*)(cws + CL_OFF)
                      + ((size_t)m * K_ + kh * 1024 + col) * D_ + krow * 8;
    const float* hn = (const float*)(cws + HN_OFF) + m * K_ + kh * 1024 + krow * 4;

    float b1[4], b2[4];
    int   k1[4];
    #pragma unroll
    for (int g = 0; g < 4; ++g) { b1[g] = b2[g] = -3.402823466e+38f; k1[g] = 0; }

    const int kbase = kh * 1024 + krow * 4;

    #pragma unroll 2
    for (int t = 0; t < 64; ++t) {
        bf16x8 ch = *(const bf16x8*)(ah + (size_t)t * (16 * D_));
        bf16x8 cl = *(const bf16x8*)(al + (size_t)t * (16 * D_));
        f32x4  c0 = *(const f32x4*)(hn + t * 16);      // already -0.5*||c||^2
        const int kt = kbase + t * 16;
        #pragma unroll
        for (int g = 0; g < 4; ++g) {
            // R6-validated 3-term split
            f32x4 a = __builtin_amdgcn_mfma_f32_16x16x32_bf16(cl, qh[g], c0, 0, 0, 0);
            a = __builtin_amdgcn_mfma_f32_16x16x32_bf16(ch, ql[g], a, 0, 0, 0);
            a = __builtin_amdgcn_mfma_f32_16x16x32_bf16(ch, qh[g], a, 0, 0, 0);
            #pragma unroll
            for (int r = 0; r < 4; ++r) {
                float s = a[r];
                b2[g] = __builtin_amdgcn_fmed3f(b1[g], b2[g], s); // running 2nd-max
                bool gt = s > b1[g];                              // strict: first-max
                k1[g] = gt ? (kt + r) : k1[g];
                b1[g] = gt ? s : b1[g];
            }
        }
    }

    // in-wave butterfly merge over the 4 code-row lane-groups (R6-validated)
    #pragma unroll
    for (int g = 0; g < 4; ++g) {
        #pragma unroll
        for (int off = 16; off <= 32; off <<= 1) {
            float ob1 = __shfl_xor(b1[g], off);
            int   ok1 = __shfl_xor(k1[g], off);
            float ob2 = __shfl_xor(b2[g], off);
            float mn  = fminf(b1[g], ob1);
            b2[g] = fmaxf(mn, fmaxf(b2[g], ob2));
            bool awin = (b1[g] > ob1) || (b1[g] == ob1 && k1[g] < ok1);
            b1[g] = awin ? b1[g] : ob1;
            k1[g] = awin ? k1[g] : ok1;
        }
    }
    if (L < 16) {
        #pragma unroll
        for (int g = 0; g < 4; ++g) {
            s_b1[kh][m][g * 16 + L] = b1[g];
            s_k1[kh][m][g * 16 + L] = k1[g];
            s_b2[kh][m][g * 16 + L] = b2[g];
        }
    }
    __syncthreads();

    // merge the two k-halves; write k1/b2m to ws (coalesced per wave: wave=m)
    if (tid < 256) {
        const int mm = tid >> 6;
        const int pl = tid & 63;
        float A1 = s_b1[0][mm][pl]; int I1 = s_k1[0][mm][pl]; float A2 = s_b2[0][mm][pl];
        float B1 = s_b1[1][mm][pl]; int J1 = s_k1[1][mm][pl]; float B2 = s_b2[1][mm][pl];
        float b2m = fmaxf(fminf(A1, B1), fmaxf(A2, B2));
        bool awin = (A1 > B1) || (A1 == B1 && I1 < J1);
        int K1 = awin ? I1 : J1;
        k1w[mm * NHW_ + posbase + pl] = K1;
        b2w[mm * NHW_ + posbase + pl] = b2m;
    }
}

// ---- kernel 3: exact fp32 confirm; rare ballot-packed cooperative exact scan ----
// 1 thread per (pos,m); t = m*NHW_ + pos (waves never straddle m: 32768%64==0).
__global__ __launch_bounds__(256) void rescore_kernel(
        const float* __restrict__ latent,
        const float* __restrict__ codebook,
        const int* __restrict__ k1w, const float* __restrict__ b2w,
        int* __restrict__ out) {
    const int t   = blockIdx.x * 256 + threadIdx.x;   // 0..131071
    const int L   = threadIdx.x & 63;
    const int mm  = t >> 15;
    const int pos = t & (NHW_ - 1);
    const int n   = pos >> 12;
    const int hw  = pos & (HW_ - 1);

    int   K1  = k1w[t];
    float b2m = b2w[t];

    const float* lq = latent + ((size_t)n * (M_ * D_) + mm * D_) * HW_ + hw;
    float q[D_];
    #pragma unroll
    for (int d = 0; d < D_; ++d) q[d] = lq[(size_t)d * HW_];
    float sx = score_fp32(q, (const float4*)(codebook + ((size_t)mm * K_ + K1) * D_));
    bool conf = (sx > b2m + EPS);
    int result = K1;

    // rare fallback (R6-validated): wave-cooperative exact scan per needy lane
    unsigned long long need = __ballot(!conf);
    while (need) {
        int bI = __ffsll(need) - 1;
        need &= need - 1;
        int pos_b = __shfl(pos, bI);
        int n_b   = pos_b >> 12;
        int hw_b  = pos_b & (HW_ - 1);
        const float* lqb = latent + ((size_t)n_b * (M_ * D_) + mm * D_) * HW_ + hw_b;
        float qq[D_];
        #pragma unroll
        for (int d = 0; d < D_; ++d) qq[d] = lqb[(size_t)d * HW_];   // broadcast
        float bs = -3.402823466e+38f;
        int   bk = 0;
        for (int i = 0; i < 32; ++i) {
            int k = L + 64 * i;
            float s = score_fp32(qq, (const float4*)(codebook + ((size_t)mm * K_ + k) * D_));
            if (s > bs || (s == bs && k < bk)) { bs = s; bk = k; }
        }
        #pragma unroll
        for (int off = 1; off <= 32; off <<= 1) {
            float os = __shfl_xor(bs, off);
            int   ok = __shfl_xor(bk, off);
            if (os > bs || (os == bs && ok < bk)) { bs = os; bk = ok; }
        }
        if (L == bI) result = bk;         // first-max over all k (matches jnp.argmax)
    }

    out[(size_t)pos * M_ + mm] = result;
}

extern "C" void kernel_launch(void* const* d_in, const int* in_sizes, int n_in,
                              void* d_out, int out_size, void* d_ws, size_t ws_size,
                              hipStream_t stream) {
    const float* latent   = (const float*)d_in[0];
    const float* codebook = (const float*)d_in[1];
    unsigned char* ws = (unsigned char*)d_ws;
    int* out = (int*)d_out;
    prep_kernel<<<(M_ * K_) / 256, 256, 0, stream>>>(codebook, ws);
    score_kernel<<<NHW_ / 64, 512, 0, stream>>>(latent, ws,
                                                (int*)(ws + K1_OFF),
                                                (float*)(ws + B2_OFF));
    rescore_kernel<<<(NHW_ * M_) / 256, 256, 0, stream>>>(latent, codebook,
                                                          (const int*)(ws + K1_OFF),
                                                          (const float*)(ws + B2_OFF),
                                                          out);
}

// Round 8
// 132.047 us; speedup vs baseline: 1.2626x; 1.2626x over previous
//
#include <hip/hip_runtime.h>

#define M_ 4
#define K_ 2048
#define D_ 32
#define HW_ 4096
#define NHW_ 32768

// Confirm margin: hard bound on |s_exact - s_approx| for the 3-term bf16 split
// <= ~3e-3 at dataset-max norms. EPS = 0.01 > 3x. conf => K1 is the unique
// exact argmax (for all k != K1: s_exact(k) <= s~(k)+eps <= b2m+EPS < sx).
// Semantics HW-validated in R6/R7 (absmax = 0).
#define EPS 0.01f

// workspace (bytes)
#define CH_OFF 0                        // bf16 hi codebook [4][2048][32] (512 KiB)
#define CL_OFF (M_*K_*D_*2)             // bf16 lo codebook              (512 KiB)
#define HN_OFF (CL_OFF*2)               // f32 -0.5*||c||^2 [4][2048]    (32 KiB)
#define K1_OFF (HN_OFF + M_*K_*4)       // i32 approx argmax [4][32768]  (512 KiB)
#define B2_OFF (K1_OFF + M_*NHW_*4)     // f32 approx 2nd max [4][32768] (512 KiB)
#define CNT_OFF (B2_OFF + M_*NHW_*4)    // i32 unconfirmed count         (16 B)
#define LIST_OFF (CNT_OFF + 16)         // i32 unconfirmed ids [4*32768] (512 KiB)

typedef __attribute__((ext_vector_type(8))) short bf16x8;
typedef __attribute__((ext_vector_type(4))) float f32x4;

__device__ __forceinline__ short bf16_rte(float x, float* back) {
    unsigned u = __float_as_uint(x);
    unsigned r = (u + 0x7FFFu + ((u >> 16) & 1u)) >> 16;
    *back = __uint_as_float(r << 16);
    return (short)(r & 0xFFFFu);
}

// ---- kernel 1: codebook -> bf16 hi/lo + (-0.5*||c||^2); zero fallback cnt ----
__global__ __launch_bounds__(256) void prep_kernel(const float* __restrict__ cb,
                                                   unsigned char* __restrict__ ws) {
    if (blockIdx.x == 0 && threadIdx.x == 0) *(int*)(ws + CNT_OFF) = 0;
    int t = blockIdx.x * 256 + threadIdx.x;          // row id = m*K_ + k
    const float* src = cb + (size_t)t * D_;
    short* dh = (short*)(ws + CH_OFF) + (size_t)t * D_;
    short* dl = (short*)(ws + CL_OFF) + (size_t)t * D_;
    float* hn = (float*)(ws + HN_OFF);
    bf16x8 vh[4], vl[4];
    float c2 = 0.f;
    #pragma unroll
    for (int d = 0; d < D_; ++d) {
        float x = src[d];
        float hf, lf;
        short hb = bf16_rte(x, &hf);
        short lb = bf16_rte(x - hf, &lf);
        vh[d >> 3][d & 7] = hb;
        vl[d >> 3][d & 7] = lb;
        c2 = fmaf(x, x, c2);
    }
    #pragma unroll
    for (int i = 0; i < 4; ++i) {
        *(bf16x8*)(dh + i * 8) = vh[i];
        *(bf16x8*)(dl + i * 8) = vl[i];
    }
    hn[t] = -0.5f * c2;
}

__device__ __forceinline__ float score_fp32(const float* __restrict__ q,
                                            const float4* __restrict__ c) {
    float d0 = 0, d1 = 0, d2 = 0, d3 = 0, e0 = 0, e1 = 0, e2 = 0, e3 = 0;
    #pragma unroll
    for (int v = 0; v < 8; ++v) {
        float4 cv = c[v];
        d0 = fmaf(q[v * 4 + 0], cv.x, d0);
        d1 = fmaf(q[v * 4 + 1], cv.y, d1);
        d2 = fmaf(q[v * 4 + 2], cv.z, d2);
        d3 = fmaf(q[v * 4 + 3], cv.w, d3);
        e0 = fmaf(cv.x, cv.x, e0);
        e1 = fmaf(cv.y, cv.y, e1);
        e2 = fmaf(cv.z, cv.z, e2);
        e3 = fmaf(cv.w, cv.w, e3);
    }
    return ((d0 + d1) + (d2 + d3)) - 0.5f * ((e0 + e1) + (e2 + e3));
}

// ---- kernel 2: R7-validated 3-term MFMA + top1(idx)/top2(val); writes k1,b2m ----
__global__ __launch_bounds__(512, 4) void score_kernel(
        const float* __restrict__ latent,
        const unsigned char* __restrict__ cws,
        int* __restrict__ k1w, float* __restrict__ b2w) {
    __shared__ float s_b1[2][M_][64];
    __shared__ int   s_k1[2][M_][64];
    __shared__ float s_b2[2][M_][64];

    const int tid  = threadIdx.x;
    const int wave = tid >> 6;
    const int L    = tid & 63;
    const int m    = wave & 3;
    const int kh   = wave >> 2;
    const int col  = L & 15;
    const int krow = L >> 4;
    const int posbase = blockIdx.x * 64;
    const int n   = posbase >> 12;
    const int hwb = posbase & (HW_ - 1);

    bf16x8 qh[4], ql[4];
    const float* lp = latent + ((size_t)n * (M_ * D_) + m * D_) * HW_ + hwb;
    #pragma unroll
    for (int g = 0; g < 4; ++g)
        #pragma unroll
        for (int j = 0; j < 8; ++j) {
            float x = lp[(size_t)(krow * 8 + j) * HW_ + g * 16 + col];
            float hf, lf;
            qh[g][j] = bf16_rte(x, &hf);
            ql[g][j] = bf16_rte(x - hf, &lf);
        }

    const short* ah = (const short*)(cws + CH_OFF)
                      + ((size_t)m * K_ + kh * 1024 + col) * D_ + krow * 8;
    const short* al = (const short*)(cws + CL_OFF)
                      + ((size_t)m * K_ + kh * 1024 + col) * D_ + krow * 8;
    const float* hn = (const float*)(cws + HN_OFF) + m * K_ + kh * 1024 + krow * 4;

    float b1[4], b2[4];
    int   k1[4];
    #pragma unroll
    for (int g = 0; g < 4; ++g) { b1[g] = b2[g] = -3.402823466e+38f; k1[g] = 0; }

    const int kbase = kh * 1024 + krow * 4;

    #pragma unroll 2
    for (int t = 0; t < 64; ++t) {
        bf16x8 ch = *(const bf16x8*)(ah + (size_t)t * (16 * D_));
        bf16x8 cl = *(const bf16x8*)(al + (size_t)t * (16 * D_));
        f32x4  c0 = *(const f32x4*)(hn + t * 16);
        const int kt = kbase + t * 16;
        #pragma unroll
        for (int g = 0; g < 4; ++g) {
            f32x4 a = __builtin_amdgcn_mfma_f32_16x16x32_bf16(cl, qh[g], c0, 0, 0, 0);
            a = __builtin_amdgcn_mfma_f32_16x16x32_bf16(ch, ql[g], a, 0, 0, 0);
            a = __builtin_amdgcn_mfma_f32_16x16x32_bf16(ch, qh[g], a, 0, 0, 0);
            #pragma unroll
            for (int r = 0; r < 4; ++r) {
                float s = a[r];
                b2[g] = __builtin_amdgcn_fmed3f(b1[g], b2[g], s);
                bool gt = s > b1[g];
                k1[g] = gt ? (kt + r) : k1[g];
                b1[g] = gt ? s : b1[g];
            }
        }
    }

    #pragma unroll
    for (int g = 0; g < 4; ++g) {
        #pragma unroll
        for (int off = 16; off <= 32; off <<= 1) {
            float ob1 = __shfl_xor(b1[g], off);
            int   ok1 = __shfl_xor(k1[g], off);
            float ob2 = __shfl_xor(b2[g], off);
            float mn  = fminf(b1[g], ob1);
            b2[g] = fmaxf(mn, fmaxf(b2[g], ob2));
            bool awin = (b1[g] > ob1) || (b1[g] == ob1 && k1[g] < ok1);
            b1[g] = awin ? b1[g] : ob1;
            k1[g] = awin ? k1[g] : ok1;
        }
    }
    if (L < 16) {
        #pragma unroll
        for (int g = 0; g < 4; ++g) {
            s_b1[kh][m][g * 16 + L] = b1[g];
            s_k1[kh][m][g * 16 + L] = k1[g];
            s_b2[kh][m][g * 16 + L] = b2[g];
        }
    }
    __syncthreads();

    if (tid < 256) {
        const int mm = tid >> 6;
        const int pl = tid & 63;
        float A1 = s_b1[0][mm][pl]; int I1 = s_k1[0][mm][pl]; float A2 = s_b2[0][mm][pl];
        float B1 = s_b1[1][mm][pl]; int J1 = s_k1[1][mm][pl]; float B2 = s_b2[1][mm][pl];
        float b2m = fmaxf(fminf(A1, B1), fmaxf(A2, B2));
        bool awin = (A1 > B1) || (A1 == B1 && I1 < J1);
        int K1 = awin ? I1 : J1;
        k1w[mm * NHW_ + posbase + pl] = K1;
        b2w[mm * NHW_ + posbase + pl] = b2m;
    }
}

// ---- kernel 3: exact fp32 confirm; append unconfirmed ids to compact list ----
__global__ __launch_bounds__(256) void confirm_kernel(
        const float* __restrict__ latent,
        const float* __restrict__ codebook,
        const int* __restrict__ k1w, const float* __restrict__ b2w,
        int* __restrict__ cnt, int* __restrict__ list,
        int* __restrict__ out) {
    const int t   = blockIdx.x * 256 + threadIdx.x;   // 0..131071 = mm*NHW_ + pos
    const int L   = threadIdx.x & 63;
    const int mm  = t >> 15;
    const int pos = t & (NHW_ - 1);
    const int n   = pos >> 12;
    const int hw  = pos & (HW_ - 1);

    int   K1  = k1w[t];
    float b2m = b2w[t];

    const float* lq = latent + ((size_t)n * (M_ * D_) + mm * D_) * HW_ + hw;
    float q[D_];
    #pragma unroll
    for (int d = 0; d < D_; ++d) q[d] = lq[(size_t)d * HW_];
    float sx = score_fp32(q, (const float4*)(codebook + ((size_t)mm * K_ + K1) * D_));
    bool conf = (sx > b2m + EPS);

    out[(size_t)pos * M_ + mm] = K1;                  // fallback overwrites if needed

    // wave-aggregated append: one atomic per wave
    unsigned long long mask = __ballot(!conf);
    if (mask) {
        int leader = __ffsll(mask) - 1;
        int base = 0;
        if (L == leader) base = atomicAdd(cnt, (int)__popcll(mask));
        base = __shfl(base, leader);
        if (!conf) {
            unsigned long long below = mask & ((1ull << L) - 1ull);
            list[base + (int)__popcll(below)] = t;
        }
    }
}

// ---- kernel 4: block-per-entry exact scan of all 2048 codes (rare) ----
__global__ __launch_bounds__(256) void fallback_kernel(
        const float* __restrict__ latent,
        const float* __restrict__ codebook,
        const int* __restrict__ cnt, const int* __restrict__ list,
        int* __restrict__ out) {
    __shared__ float s_bs[4];
    __shared__ int   s_bk[4];
    const int tid  = threadIdx.x;
    const int wave = tid >> 6;
    const int L    = tid & 63;
    const int ncnt = *cnt;

    for (int e = blockIdx.x; e < ncnt; e += gridDim.x) {
        int t   = list[e];
        int mm  = t >> 15;
        int pos = t & (NHW_ - 1);
        int n   = pos >> 12;
        int hw  = pos & (HW_ - 1);
        const float* lq = latent + ((size_t)n * (M_ * D_) + mm * D_) * HW_ + hw;
        float q[D_];
        #pragma unroll
        for (int d = 0; d < D_; ++d) q[d] = lq[(size_t)d * HW_];   // broadcast

        float bs = -3.402823466e+38f;
        int   bk = 0;
        #pragma unroll
        for (int i = 0; i < 8; ++i) {                  // k = tid + 256*i, ascending
            int k = tid + 256 * i;
            float s = score_fp32(q, (const float4*)(codebook + ((size_t)mm * K_ + k) * D_));
            if (s > bs || (s == bs && k < bk)) { bs = s; bk = k; }
        }
        #pragma unroll
        for (int off = 1; off <= 32; off <<= 1) {
            float os = __shfl_xor(bs, off);
            int   ok = __shfl_xor(bk, off);
            if (os > bs || (os == bs && ok < bk)) { bs = os; bk = ok; }
        }
        if (L == 0) { s_bs[wave] = bs; s_bk[wave] = bk; }
        __syncthreads();
        if (tid == 0) {
            float fs = s_bs[0]; int fk = s_bk[0];
            #pragma unroll
            for (int w = 1; w < 4; ++w) {
                float os = s_bs[w]; int ok = s_bk[w];
                if (os > fs || (os == fs && ok < fk)) { fs = os; fk = ok; }
            }
            out[(size_t)pos * M_ + mm] = fk;           // first-max over all k
        }
        __syncthreads();
    }
}

extern "C" void kernel_launch(void* const* d_in, const int* in_sizes, int n_in,
                              void* d_out, int out_size, void* d_ws, size_t ws_size,
                              hipStream_t stream) {
    const float* latent   = (const float*)d_in[0];
    const float* codebook = (const float*)d_in[1];
    unsigned char* ws = (unsigned char*)d_ws;
    int* out = (int*)d_out;
    prep_kernel<<<(M_ * K_) / 256, 256, 0, stream>>>(codebook, ws);
    score_kernel<<<NHW_ / 64, 512, 0, stream>>>(latent, ws,
                                                (int*)(ws + K1_OFF),
                                                (float*)(ws + B2_OFF));
    confirm_kernel<<<(NHW_ * M_) / 256, 256, 0, stream>>>(latent, codebook,
                                                          (const int*)(ws + K1_OFF),
                                                          (const float*)(ws + B2_OFF),
                                                          (int*)(ws + CNT_OFF),
                                                          (int*)(ws + LIST_OFF),
                                                          out);
    fallback_kernel<<<1024, 256, 0, stream>>>(latent, codebook,
                                              (const int*)(ws + CNT_OFF),
                                              (const int*)(ws + LIST_OFF),
                                              out);
}